// Round 5
// baseline (37.318 us; speedup 1.0000x reference)
//
#include <hip/hip_runtime.h>
#include <hip/hip_fp16.h>

#define BB 16
#define DD 64
#define HH 128
#define WW 240
#define HW (HH * WW)     // 30720, divisible by BLK
#define NS 10            // samples per level
#define NL 3             // pyramid levels
#define BLK 256
#define NWORD (DD / 2)   // 32 packed d-pair words per pixel
#define GRID 512         // 2 blocks/CU (64 KiB LDS each)
#define NTILE (BB * HW / BLK)   // 1920 tiles of 256 pixels

__device__ inline unsigned pack2h(float lo, float hi) {
    __half2 h = __floats2half2_rn(lo, hi);
    return *reinterpret_cast<unsigned*>(&h);
}
__device__ inline float2 unpack2h(unsigned u) {
    __half2 h = *reinterpret_cast<__half2*>(&u);
    return __half22float2(h);
}
__device__ inline float exth(unsigned u, int sel) {
    unsigned short us = (unsigned short)(u >> (sel << 4));
    __half_raw hr; hr.x = us;
    return __half2float(*reinterpret_cast<__half*>(&hr));
}

__global__ __launch_bounds__(BLK) void pcv_kernel(
    const float* __restrict__ cv,
    const int* __restrict__ radius_p,
    const float* __restrict__ disp_in,
    float* __restrict__ out)
{
    // word-major packed d-pairs: lane i always hits bank i%32 -> conflict-free gather
    __shared__ unsigned ldsw[2][NWORD * BLK];   // 2 x 32 KiB double buffer
    const int tid = threadIdx.x;
    const int bid = blockIdx.x;
    const int q  = tid & 63;        // float4 slot within a d-row
    const int jb = tid >> 6;        // wave id 0..3

    const float r = (float)(*radius_p);
    const float interval = (float)((2.0 * (double)r) / 9.0);  // match Python double math

    const int ntiles = (NTILE - bid + GRID - 1) / GRID;  // 3 or 4, block-uniform

    float4 rv[16];   // in-flight tile (fully unrolled static indexing -> stays in VGPRs)
    float  dsp;

    // ---- prologue: issue loads for tile 0 ----
    {
        const int t = bid;
        const int pb = t * BLK;
        const int b = pb / HW;
        const int pixbase = pb - b * HW;
        const float* src = cv + (size_t)b * DD * HW + pixbase;
        #pragma unroll
        for (int it = 0; it < 8; ++it) {
            const int j = it * 4 + jb;
            rv[2 * it]     = *reinterpret_cast<const float4*>(src + (size_t)(2 * j)     * HW + q * 4);
            rv[2 * it + 1] = *reinterpret_cast<const float4*>(src + (size_t)(2 * j + 1) * HW + q * 4);
        }
        dsp = disp_in[pb + tid];
    }

    int cur = 0;
    for (int k = 0; k < ntiles; ++k) {
        const int t = bid + k * GRID;
        const int pb = t * BLK;
        const int b = pb / HW;
        const int pix = pb - b * HW + tid;

        // ---- pack current tile into LDS (compiler inserts vmcnt waits on rv) ----
        unsigned* buf = &ldsw[cur][0];
        #pragma unroll
        for (int it = 0; it < 8; ++it) {
            const int j = it * 4 + jb;
            uint4 wv;
            wv.x = pack2h(rv[2 * it].x, rv[2 * it + 1].x);
            wv.y = pack2h(rv[2 * it].y, rv[2 * it + 1].y);
            wv.z = pack2h(rv[2 * it].z, rv[2 * it + 1].z);
            wv.w = pack2h(rv[2 * it].w, rv[2 * it + 1].w);
            *reinterpret_cast<uint4*>(&buf[j * BLK + q * 4]) = wv;
        }
        const float disp = dsp;

        // ---- issue next tile's loads: stay in flight across the barrier ----
        if (k + 1 < ntiles) {
            const int tn = bid + (k + 1) * GRID;
            const int pbn = tn * BLK;
            const int bn = pbn / HW;
            const int pixbase_n = pbn - bn * HW;
            const float* srcn = cv + (size_t)bn * DD * HW + pixbase_n;
            #pragma unroll
            for (int it = 0; it < 8; ++it) {
                const int j = it * 4 + jb;
                rv[2 * it]     = *reinterpret_cast<const float4*>(srcn + (size_t)(2 * j)     * HW + q * 4);
                rv[2 * it + 1] = *reinterpret_cast<const float4*>(srcn + (size_t)(2 * j + 1) * HW + q * 4);
            }
            dsp = disp_in[pbn + tid];
        }

        // raw barrier: drain LDS writes only, leave global loads in flight
        asm volatile("s_waitcnt lgkmcnt(0)\n\ts_barrier" ::: "memory");

        // ---- compute + store current tile ----
        float* outp = out + (size_t)b * (NL * NS) * HW + pix;
        float rd = disp;
        int Dl = DD;
        #pragma unroll
        for (int lvl = 0; lvl < NL; ++lvl) {
            const float lower = rd - r;
            const float dmax = (float)(Dl - 1);
            #pragma unroll
            for (int s = 0; s < NS; ++s) {
                float cand = lower + (float)s * interval;
                float cc = fminf(fmaxf(ceilf(cand),  0.0f), dmax);
                float fc = fminf(fmaxf(floorf(cand), 0.0f), dmax);
                float fr = cc - cand;      // floor_rate (post-clip, as in reference)
                float cr = 1.0f - fr;
                int ic = (int)cc;
                int fi = (int)fc;
                float vc, vf;
                if (lvl == 0) {
                    unsigned uf = buf[(fi >> 1) * BLK + tid];
                    unsigned uc = buf[(ic >> 1) * BLK + tid];
                    vf = exth(uf, fi & 1);
                    vc = exth(uc, ic & 1);
                } else if (lvl == 1) {
                    float2 a = unpack2h(buf[fi * BLK + tid]);
                    float2 c = unpack2h(buf[ic * BLK + tid]);
                    vf = 0.5f * (a.x + a.y);
                    vc = 0.5f * (c.x + c.y);
                } else {
                    float2 a0 = unpack2h(buf[(2 * fi)     * BLK + tid]);
                    float2 a1 = unpack2h(buf[(2 * fi + 1) * BLK + tid]);
                    float2 c0 = unpack2h(buf[(2 * ic)     * BLK + tid]);
                    float2 c1 = unpack2h(buf[(2 * ic + 1) * BLK + tid]);
                    vf = 0.5f * (0.5f * (a0.x + a0.y) + 0.5f * (a1.x + a1.y));
                    vc = 0.5f * (0.5f * (c0.x + c0.y) + 0.5f * (c1.x + c1.y));
                }
                outp[(size_t)(lvl * NS + s) * HW] = vc * cr + vf * fr;
            }
            rd *= 0.5f;
            Dl >>= 1;
        }
        cur ^= 1;
        // no second barrier needed: next pack targets the other buffer, and
        // barrier(k+1) transitively orders pack(k+2) after all compute(k).
    }
}

extern "C" void kernel_launch(void* const* d_in, const int* in_sizes, int n_in,
                              void* d_out, int out_size, void* d_ws, size_t ws_size,
                              hipStream_t stream) {
    const float* cv     = (const float*)d_in[0];
    const int*   radius = (const int*)  d_in[1];
    const float* disp   = (const float*)d_in[2];
    float*       out    = (float*)d_out;

    pcv_kernel<<<dim3(GRID), dim3(BLK), 0, stream>>>(cv, radius, disp, out);
}

// Round 6
// 33.638 us; speedup vs baseline: 1.1094x; 1.1094x over previous
//
#include <hip/hip_runtime.h>
#include <hip/hip_fp16.h>

#define BB 16
#define DD 64
#define HH 128
#define WW 240
#define HW (HH * WW)       // 30720
#define NS 10              // samples per level
#define NL 3               // pyramid levels
#define BLK 256
#define TPIX 128           // pixels per tile (2 threads/pixel)
#define NWORD (DD / 2)     // 32 packed d-pair words per pixel
#define NTILE (BB * HW / TPIX)  // 3840
#define GRID 960           // NTILE/GRID == 4 exactly -> zero imbalance
#define KITER (NTILE / GRID)    // 4

__device__ inline unsigned pack2h(float lo, float hi) {
    __half2 h = __floats2half2_rn(lo, hi);
    return *reinterpret_cast<unsigned*>(&h);
}
__device__ inline float2 unpack2h(unsigned u) {
    __half2 h = *reinterpret_cast<__half2*>(&u);
    return __half22float2(h);
}
__device__ inline float exth(unsigned u, int sel) {
    unsigned short us = (unsigned short)(u >> (sel << 4));
    __half_raw hr; hr.x = us;
    return __half2float(*reinterpret_cast<__half*>(&hr));
}

__global__ __launch_bounds__(BLK, 4) void pcv_kernel(
    const float* __restrict__ cv,
    const int* __restrict__ radius_p,
    const float* __restrict__ disp_in,
    float* __restrict__ out)
{
    // word-major packed d-pairs: gather bank = pix%32, independent of gathered d
    __shared__ unsigned ldsw[2][NWORD * TPIX];   // 2 x 16 KiB double buffer
    const int tid = threadIdx.x;
    const int bid = blockIdx.x;
    const int slot = tid & 31;     // float4 slot within a d-row (32 slots * 4 pix = 128)
    const int jg   = tid >> 5;     // j-row group 0..7 (staging)
    const int px   = tid & 127;    // pixel within tile (compute)
    const int shalf = tid >> 7;    // 0/1: which 5-sample half this thread computes

    const float r = (float)(*radius_p);
    const float interval = (float)((2.0 * (double)r) / 9.0);  // match Python double math

    float4 rva[4], rvb[4];   // in-flight tile: rows 2j / 2j+1
    float  dsp;

    // ---- prologue: issue loads for tile `bid` ----
    {
        const int pb = bid * TPIX;
        const int b = pb / HW;
        const int pixbase = pb - b * HW;
        const float* src = cv + (size_t)b * DD * HW + pixbase;
        #pragma unroll
        for (int it = 0; it < 4; ++it) {
            const int j = it * 8 + jg;
            rva[it] = *reinterpret_cast<const float4*>(src + (size_t)(2 * j)     * HW + slot * 4);
            rvb[it] = *reinterpret_cast<const float4*>(src + (size_t)(2 * j + 1) * HW + slot * 4);
        }
        dsp = disp_in[pb + px];
    }

    int cur = 0;
    for (int k = 0; k < KITER; ++k) {
        const int t = bid + k * GRID;
        const int pb = t * TPIX;
        const int b = pb / HW;              // TPIX divides HW: tile never crosses b
        const int pix = pb - b * HW + px;

        // ---- pack current tile into LDS (compiler waits vmcnt on rv use) ----
        unsigned* buf = &ldsw[cur][0];
        #pragma unroll
        for (int it = 0; it < 4; ++it) {
            const int j = it * 8 + jg;
            uint4 wv;
            wv.x = pack2h(rva[it].x, rvb[it].x);
            wv.y = pack2h(rva[it].y, rvb[it].y);
            wv.z = pack2h(rva[it].z, rvb[it].z);
            wv.w = pack2h(rva[it].w, rvb[it].w);
            *reinterpret_cast<uint4*>(&buf[j * TPIX + slot * 4]) = wv;
        }
        const float disp = dsp;

        // ---- issue next tile's loads: stay in flight across the barrier ----
        if (k + 1 < KITER) {
            const int pbn = (t + GRID) * TPIX;
            const int bn = pbn / HW;
            const float* srcn = cv + (size_t)bn * DD * HW + (pbn - bn * HW);
            #pragma unroll
            for (int it = 0; it < 4; ++it) {
                const int j = it * 8 + jg;
                rva[it] = *reinterpret_cast<const float4*>(srcn + (size_t)(2 * j)     * HW + slot * 4);
                rvb[it] = *reinterpret_cast<const float4*>(srcn + (size_t)(2 * j + 1) * HW + slot * 4);
            }
            dsp = disp_in[pbn + px];
        }

        // raw barrier: drain LDS writes only, leave global loads in flight
        asm volatile("s_waitcnt lgkmcnt(0)\n\ts_barrier" ::: "memory");

        // ---- compute + store current tile: this thread's 5 samples per level ----
        float* outp = out + (size_t)b * (NL * NS) * HW + pix;
        float rd = disp;
        int Dl = DD;
        #pragma unroll
        for (int lvl = 0; lvl < NL; ++lvl) {
            const float lower = rd - r;
            const float dmax = (float)(Dl - 1);
            #pragma unroll
            for (int s5 = 0; s5 < 5; ++s5) {
                const int s = shalf * 5 + s5;
                float cand = lower + (float)s * interval;
                float cc = fminf(fmaxf(ceilf(cand),  0.0f), dmax);
                float fc = fminf(fmaxf(floorf(cand), 0.0f), dmax);
                float fr = cc - cand;      // floor_rate (post-clip, as in reference)
                float cr = 1.0f - fr;
                int ic = (int)cc;
                int fi = (int)fc;
                float vc, vf;
                if (lvl == 0) {
                    unsigned uf = buf[(fi >> 1) * TPIX + px];
                    unsigned uc = buf[(ic >> 1) * TPIX + px];
                    vf = exth(uf, fi & 1);
                    vc = exth(uc, ic & 1);
                } else if (lvl == 1) {
                    float2 a = unpack2h(buf[fi * TPIX + px]);
                    float2 c = unpack2h(buf[ic * TPIX + px]);
                    vf = 0.5f * (a.x + a.y);
                    vc = 0.5f * (c.x + c.y);
                } else {
                    float2 a0 = unpack2h(buf[(2 * fi)     * TPIX + px]);
                    float2 a1 = unpack2h(buf[(2 * fi + 1) * TPIX + px]);
                    float2 c0 = unpack2h(buf[(2 * ic)     * TPIX + px]);
                    float2 c1 = unpack2h(buf[(2 * ic + 1) * TPIX + px]);
                    vf = 0.5f * (0.5f * (a0.x + a0.y) + 0.5f * (a1.x + a1.y));
                    vc = 0.5f * (0.5f * (c0.x + c0.y) + 0.5f * (c1.x + c1.y));
                }
                outp[(size_t)(lvl * NS + s) * HW] = vc * cr + vf * fr;
            }
            rd *= 0.5f;
            Dl >>= 1;
        }
        cur ^= 1;
        // single barrier/iter is race-free: pack(k+2) into buf A follows
        // barrier(k+1), which transitively follows every wave's compute(k) on A.
    }
}

extern "C" void kernel_launch(void* const* d_in, const int* in_sizes, int n_in,
                              void* d_out, int out_size, void* d_ws, size_t ws_size,
                              hipStream_t stream) {
    const float* cv     = (const float*)d_in[0];
    const int*   radius = (const int*)  d_in[1];
    const float* disp   = (const float*)d_in[2];
    float*       out    = (float*)d_out;

    pcv_kernel<<<dim3(GRID), dim3(BLK), 0, stream>>>(cv, radius, disp, out);
}